// Round 6
// baseline (1263.054 us; speedup 1.0000x reference)
//
#include <hip/hip_runtime.h>
#include <hip/hip_bf16.h>

#define B_  32
#define T_  1024
#define C_  8
#define K_  10
#define LH_ 32

using f2 = __attribute__((ext_vector_type(2))) float;

// ---------------------------------------------------------------------------
// workspace layout (floats)
// ---------------------------------------------------------------------------
#define WS_H    0
#define WS_SQ   1048576            // B*T*32
#define WS_ACC  (WS_SQ + 32768)
#define WS_WT   (WS_ACC + 1024)   // transposed weights, 106496 floats
#define WS_A0   (WS_WT + 106496)  // [B][27][32]
#define WS_O0   (WS_A0 + 27648)   // [B][25][32]
#define WS_A1   (WS_O0 + 25600)   // [B][21][64]
#define WS_O1   (WS_A1 + 43008)   // [B][17][64]
#define WS_A2   (WS_O1 + 34816)   // [B][9][128]
#define WS_Y    (WS_A2 + 36864)   // [B][128]

#define WT_C1_0 0
#define WT_C2_0 768
#define WT_DW0  3840
#define WT_C1_1 4096
#define WT_C2_1 10240
#define WT_DW1  22528
#define WT_C1_2 24576
#define WT_C2_2 49152
#define WT_DW2  98304
#define WT_TOTAL 106496

// ---------------------------------------------------------------------------
// K1: h = x @ pw + pb (fp32), sq = ||h||^2, zero acc
// ---------------------------------------------------------------------------
__global__ __launch_bounds__(256) void k_project(
    const float* __restrict__ x,
    const float* __restrict__ pw,
    const float* __restrict__ pb,
    float* __restrict__ h, float* __restrict__ sq, float* __restrict__ acc)
{
    int gid = blockIdx.x * 256 + threadIdx.x;
    if (gid < B_ * LH_) acc[gid] = 0.f;
    int row = gid >> 5;
    int i   = gid & 31;
    const float* xr = x + (size_t)row * C_;
    float4 x0 = *(const float4*)xr;
    float4 x1 = *(const float4*)(xr + 4);
    float hv = pb[i];
    hv = fmaf(x0.x, pw[0 * LH_ + i], hv);
    hv = fmaf(x0.y, pw[1 * LH_ + i], hv);
    hv = fmaf(x0.z, pw[2 * LH_ + i], hv);
    hv = fmaf(x0.w, pw[3 * LH_ + i], hv);
    hv = fmaf(x1.x, pw[4 * LH_ + i], hv);
    hv = fmaf(x1.y, pw[5 * LH_ + i], hv);
    hv = fmaf(x1.z, pw[6 * LH_ + i], hv);
    hv = fmaf(x1.w, pw[7 * LH_ + i], hv);
    h[(size_t)row * LH_ + i] = hv;
    float e = hv * hv;
#pragma unroll
    for (int off = 1; off < 32; off <<= 1) e += __shfl_xor(e, off, 64);
    if (i == 0) sq[row] = e;
}

// ---------------------------------------------------------------------------
// DPP full-wave min (u32): row_shr 1/2/4/8, row_bcast15, row_bcast31 -> lane63
// ---------------------------------------------------------------------------
__device__ __forceinline__ unsigned wave_min_u32(unsigned v)
{
#define DPP_MIN(ctrl) \
    v = min(v, (unsigned)__builtin_amdgcn_update_dpp((int)v, (int)v, ctrl, 0xF, 0xF, false))
    DPP_MIN(0x111);  // row_shr:1
    DPP_MIN(0x112);  // row_shr:2
    DPP_MIN(0x114);  // row_shr:4
    DPP_MIN(0x118);  // row_shr:8
    DPP_MIN(0x142);  // row_bcast:15
    DPP_MIN(0x143);  // row_bcast:31
#undef DPP_MIN
    return (unsigned)__builtin_amdgcn_readlane((int)v, 63);
}

// ---------------------------------------------------------------------------
// K2a (preferred): whole h[b] in LDS (1024 rows x stride 36 = 144KB),
// 1024-thread block, ONE barrier, DPP selection (no ds_swizzle).
// ---------------------------------------------------------------------------
#define SPAD 36

__global__ __launch_bounds__(1024, 4) void k_laplace_big(
    const float* __restrict__ h, const float* __restrict__ sq,
    float* __restrict__ acc)
{
    extern __shared__ float lds[];
    float* tile = lds;                  // [1024][36]
    float* wacc = lds + 1024 * SPAD;    // [16][32]

    const int tid = threadIdx.x;
    const int wv  = tid >> 6;                 // 0..15
    const int ln  = tid & 63;
    const int b   = blockIdx.x >> 5;          // 32 qgroups per batch
    const int t0  = (blockIdx.x & 31) * 32;   // 32 queries per block
    const int tq0 = t0 + wv * 2;

    const float* hb  = h  + (size_t)b * T_ * LH_;
    const float* sqb = sq + b * T_;

    {   // stage h[b]: thread tid -> row tid (8 coalesced f4 per thread)
        const float4* src = (const float4*)(hb + (size_t)tid * LH_);
        float* dst = &tile[tid * SPAD];
#pragma unroll
        for (int c4 = 0; c4 < 8; ++c4)
            *(float4*)&dst[c4 * 4] = src[c4];
    }

    f2    q[2][16];
    float sqq[2];
#pragma unroll
    for (int u = 0; u < 2; ++u) {
        const float* qr = hb + (size_t)(tq0 + u) * LH_;
#pragma unroll
        for (int j = 0; j < 16; ++j) q[u][j] = *(const f2*)&qr[2 * j];
        sqq[u] = sqb[tq0 + u];
    }
    __syncthreads();   // the only barrier before the final reduce

    unsigned kk[2][16];   // kk[u][c] holds key for s = c*64 + ln
#pragma unroll
    for (int c = 0; c < 16; ++c) {
        const int s = c * 64 + ln;
        const float* hs = &tile[s * SPAD];
        f2 d0 = {0.f, 0.f}, d1 = {0.f, 0.f};
#pragma unroll
        for (int j4 = 0; j4 < 8; ++j4) {
            float4 hv4 = *(const float4*)(hs + j4 * 4);
            f2 h0 = {hv4.x, hv4.y};
            f2 h1 = {hv4.z, hv4.w};
            d0 = __builtin_elementwise_fma(h0, q[0][2 * j4 + 0], d0);
            d0 = __builtin_elementwise_fma(h1, q[0][2 * j4 + 1], d0);
            d1 = __builtin_elementwise_fma(h0, q[1][2 * j4 + 0], d1);
            d1 = __builtin_elementwise_fma(h1, q[1][2 * j4 + 1], d1);
        }
        const float sqs = sqb[s];
        float d2a = fmaxf(sqq[0] + sqs - 2.f * (d0.x + d0.y), 0.f);
        float d2b = fmaxf(sqq[1] + sqs - 2.f * (d1.x + d1.y), 0.f);
        unsigned ka = (__float_as_uint(d2a) & 0xFFFFFC00u) | (unsigned)s;
        unsigned kb = (__float_as_uint(d2b) & 0xFFFFFC00u) | (unsigned)s;
        if (s == tq0 + 0) ka = 0xFFFFFC00u | (unsigned)s;
        if (s == tq0 + 1) kb = 0xFFFFFC00u | (unsigned)s;
        kk[0][c] = ka;
        kk[1][c] = kb;
    }

    float racc = 0.f;

    auto process = [&](unsigned (&ku)[16], int tq) {
        int   sk[K_];
        float wk[K_];
        unsigned g2[4];
#pragma unroll
        for (int g = 0; g < 4; ++g)
            g2[g] = min(min(ku[4 * g], ku[4 * g + 1]), min(ku[4 * g + 2], ku[4 * g + 3]));
#pragma unroll
        for (int r = 0; r < K_; ++r) {
            unsigned m  = min(min(g2[0], g2[1]), min(g2[2], g2[3]));
            unsigned mu = wave_min_u32(m);            // wave-uniform (SGPR)
            int s_win = (int)(mu & 1023u);
            sk[r] = s_win;
            wk[r] = __expf(-0.5f * __uint_as_float(mu & 0xFFFFFC00u));
            const int  c = s_win >> 6;                // scalar branch target
            const bool winlane = ((s_win & 63) == ln);
#pragma unroll
            for (int cc = 0; cc < 16; ++cc) if (cc == c) {
                ku[cc] = winlane ? 0xFFFFFFFFu : ku[cc];
                const int g = cc >> 2;
                g2[g] = min(min(ku[4 * g], ku[4 * g + 1]), min(ku[4 * g + 2], ku[4 * g + 3]));
            }
        }
        const int i = ln & 31;
        const float qi = tile[tq * SPAD + i];
        float W = 0.f, sm = 0.f;
#pragma unroll
        for (int k = 0; k < K_; ++k) {
            W += wk[k];
            sm = fmaf(wk[k], tile[sk[k] * SPAD + i], sm);   // 32-bank clean gather
        }
        sm *= __builtin_amdgcn_rcpf(W + 1e-8f);
        float z  = qi - sm;
        float ex = __expf(2.f * z);                   // tanh(z) = 1 - 2/(e^{2z}+1)
        racc += 1.f - 2.f * __builtin_amdgcn_rcpf(ex + 1.f);
    };

    process(kk[0], tq0 + 0);
    process(kk[1], tq0 + 1);

    if (ln < 32) wacc[wv * 32 + ln] = racc;
    __syncthreads();
    if (tid < 32) {
        float tot = 0.f;
#pragma unroll
        for (int w = 0; w < 16; ++w) tot += wacc[w * 32 + tid];
        atomicAdd(&acc[b * LH_ + tid], tot);
    }
}

// ---------------------------------------------------------------------------
// K2b (fallback, R4-proven): 128-row tiles, 8 restages, shfl selection.
// ---------------------------------------------------------------------------
#define STILE 128

__global__ __launch_bounds__(256, 2) void k_laplace_tiled(
    const float* __restrict__ h, const float* __restrict__ sq,
    float* __restrict__ acc)
{
    __shared__ float tile[STILE * SPAD];
    __shared__ float wacc[4 * 32];
    __shared__ float qbuf[8 * 32];

    const int tid = threadIdx.x;
    const int wv  = tid >> 6;
    const int ln  = tid & 63;
    const int b   = blockIdx.x >> 7;
    const int t0  = (blockIdx.x & 127) * 8;
    const int tA  = t0 + wv * 2;
    const int tB  = tA + 1;

    const float* hb  = h  + (size_t)b * T_ * LH_;
    const float* sqb = sq + b * T_;

    if (ln < 32) {
        qbuf[(wv * 2 + 0) * 32 + ln] = hb[tA * LH_ + ln];
        qbuf[(wv * 2 + 1) * 32 + ln] = hb[tB * LH_ + ln];
    }
    float qA[32], qB[32];
#pragma unroll
    for (int i = 0; i < 32; ++i) { qA[i] = hb[tA * LH_ + i]; qB[i] = hb[tB * LH_ + i]; }
    const float sqA = sqb[tA], sqB = sqb[tB];

    unsigned kA[16], kB[16];

    for (int tl = 0; tl < T_ / STILE; ++tl) {
        const int s_base = tl * STILE;
        __syncthreads();
#pragma unroll
        for (int u = 0; u < 4; ++u) {
            int e4 = u * 256 + tid;
            int r  = e4 >> 3, c4 = e4 & 7;
            float4 val = *(const float4*)(hb + (size_t)(s_base + r) * LH_ + c4 * 4);
            *(float4*)&tile[r * SPAD + c4 * 4] = val;
        }
        __syncthreads();
#pragma unroll
        for (int sub = 0; sub < 2; ++sub) {
            const int sr = sub * 64 + ln;
            const int s  = s_base + sr;
            const float* hs = &tile[sr * SPAD];
            float dA = 0.f, dB = 0.f;
#pragma unroll
            for (int q4 = 0; q4 < 8; ++q4) {
                float4 hv4 = *(const float4*)(hs + q4 * 4);
                dA = fmaf(hv4.x, qA[q4 * 4 + 0], dA); dB = fmaf(hv4.x, qB[q4 * 4 + 0], dB);
                dA = fmaf(hv4.y, qA[q4 * 4 + 1], dA); dB = fmaf(hv4.y, qB[q4 * 4 + 1], dB);
                dA = fmaf(hv4.z, qA[q4 * 4 + 2], dA); dB = fmaf(hv4.z, qB[q4 * 4 + 2], dB);
                dA = fmaf(hv4.w, qA[q4 * 4 + 3], dA); dB = fmaf(hv4.w, qB[q4 * 4 + 3], dB);
            }
            const float sqs = sqb[s];
            float d2A = fmaxf(sqA + sqs - 2.f * dA, 0.f);
            float d2B = fmaxf(sqB + sqs - 2.f * dB, 0.f);
            unsigned keyA = (__float_as_uint(d2A) & 0xFFFFFC00u) | (unsigned)s;
            unsigned keyB = (__float_as_uint(d2B) & 0xFFFFFC00u) | (unsigned)s;
            if (s == tA) keyA = 0xFFFFFC00u | (unsigned)s;
            if (s == tB) keyB = 0xFFFFFC00u | (unsigned)s;
            kA[tl * 2 + sub] = keyA;
            kB[tl * 2 + sub] = keyB;
        }
    }

    float racc = 0.f;

    auto process = [&](unsigned (&ku)[16], int qslot) {
        int   sk[K_];
        float wk[K_];
        unsigned g2[4];
#pragma unroll
        for (int g = 0; g < 4; ++g)
            g2[g] = min(min(ku[4 * g], ku[4 * g + 1]), min(ku[4 * g + 2], ku[4 * g + 3]));
#pragma unroll
        for (int r = 0; r < K_; ++r) {
            unsigned m = min(min(g2[0], g2[1]), min(g2[2], g2[3]));
            unsigned mu = wave_min_u32(m);
            int s_win = (int)(mu & 1023u);
            sk[r] = s_win;
            wk[r] = __expf(-0.5f * __uint_as_float(mu & 0xFFFFFC00u));
            const int c = s_win >> 6;
            const bool winlane = ((s_win & 63) == ln);
#pragma unroll
            for (int cc = 0; cc < 16; ++cc) if (cc == c) {
                ku[cc] = winlane ? 0xFFFFFFFFu : ku[cc];
                const int g = cc >> 2;
                g2[g] = min(min(ku[4 * g], ku[4 * g + 1]), min(ku[4 * g + 2], ku[4 * g + 3]));
            }
        }
        const int i = ln & 31;
        const float qi = qbuf[qslot * 32 + i];
        float W = 0.f, sm = 0.f;
#pragma unroll
        for (int k = 0; k < K_; ++k) {
            W += wk[k];
            sm = fmaf(wk[k], hb[(size_t)sk[k] * LH_ + i], sm);
        }
        sm *= __builtin_amdgcn_rcpf(W + 1e-8f);
        float z  = qi - sm;
        float ex = __expf(2.f * z);
        racc += 1.f - 2.f * __builtin_amdgcn_rcpf(ex + 1.f);
    };

    process(kA, wv * 2 + 0);
    process(kB, wv * 2 + 1);

    if (ln < 32) wacc[wv * 32 + ln] = racc;
    __syncthreads();
    if (tid < 32) {
        float tot = wacc[tid] + wacc[32 + tid] + wacc[64 + tid] + wacc[96 + tid];
        atomicAdd(&acc[b * LH_ + tid], tot);
    }
}

// ---------------------------------------------------------------------------
// Weight transpose + TCN stages + head (unchanged from R4/R5)
// ---------------------------------------------------------------------------
struct WSegs { const float* src[9]; int k3[9]; int colog2[9]; int off[10]; };

__global__ __launch_bounds__(256) void k_wT(WSegs S, float* __restrict__ wT)
{
    int gid = blockIdx.x * 256 + threadIdx.x;
    if (gid >= WT_TOTAL) return;
#pragma unroll
    for (int s = 0; s < 9; ++s) {
        if (gid >= S.off[s] && gid < S.off[s + 1]) {
            int local = gid - S.off[s];
            int k = local >> S.colog2[s];
            int o = local & ((1 << S.colog2[s]) - 1);
            wT[gid] = S.src[s][o * S.k3[s] + k];
        }
    }
}

template<int CI, int CO, int DIL, int ROWS>
__global__ __launch_bounds__(256) void k_conv(
    const float* __restrict__ in, int in_bs, int in_roff,
    const float* __restrict__ wT, const float* __restrict__ bias,
    float* __restrict__ out)
{
    const int e = blockIdx.x * 256 + threadIdx.x;
    const int b = blockIdx.y;
    if (e >= ROWS * CO) return;
    const int r = e / CO, o = e % CO;
    const float* inb = in + (size_t)b * in_bs + (size_t)in_roff * CI;
    float s = bias[o];
    for (int i = 0; i < CI; ++i)
#pragma unroll
        for (int j = 0; j < 3; ++j)
            s = fmaf(wT[(i * 3 + j) * CO + o], inb[(r + DIL * j) * CI + i], s);
    out[(size_t)b * (ROWS * CO) + e] = fmaxf(s, 0.f);
}

template<int CI, int CO, int DIL, int ROWS, int RCI>
__global__ __launch_bounds__(256) void k_convres(
    const float* __restrict__ in, int in_bs,
    const float* __restrict__ wT2, const float* __restrict__ b2,
    const float* __restrict__ res, int res_bs, int res_roff,
    const float* __restrict__ wTd, const float* __restrict__ db,
    float* __restrict__ out)
{
    const int e = blockIdx.x * 256 + threadIdx.x;
    const int b = blockIdx.y;
    if (e >= ROWS * CO) return;
    const int r = e / CO, o = e % CO;
    const float* inb = in + (size_t)b * in_bs;
    float s = b2[o];
    for (int i = 0; i < CI; ++i)
#pragma unroll
        for (int j = 0; j < 3; ++j)
            s = fmaf(wT2[(i * 3 + j) * CO + o], inb[(r + DIL * j) * CI + i], s);
    s = fmaxf(s, 0.f);
    const float* rb = res + (size_t)b * res_bs + (size_t)(res_roff + r) * RCI;
    float rs = db[o];
    for (int i = 0; i < RCI; ++i)
        rs = fmaf(wTd[i * CO + o], rb[i], rs);
    out[(size_t)b * (ROWS * CO) + e] = fmaxf(s + rs, 0.f);
}

struct HeadW {
    const float *ow, *ob, *head_w, *head_b;
    const float *f1w, *f1b, *f2w, *f2b, *r1w, *r1b, *r2w, *r2b;
};

__global__ __launch_bounds__(256) void k_head(
    const float* __restrict__ y, const float* __restrict__ acc,
    HeadW hw, float* __restrict__ out)
{
    const int b = blockIdx.x, tid = threadIdx.x;
    __shared__ float yv[128], v96[96], h1[256], h2[256], h3[128];

    if (tid < 128) yv[tid] = y[b * 128 + tid];
    else if (tid < 160) {
        int j = tid - 128;
        float s = hw.ob[j];
        for (int i = 0; i < 32; ++i)
            s = fmaf(acc[b * 32 + i] * (1.f / 1024.f), hw.ow[i * 32 + j], s);
        v96[j] = s;
    }
    __syncthreads();
    if (tid < 64) {
        float s = hw.head_b[tid];
        for (int i = 0; i < 128; ++i)
            s = fmaf(yv[i], hw.head_w[i * 64 + tid], s);
        v96[32 + tid] = s;
    }
    __syncthreads();
    {
        float s = hw.f1b[tid];
        for (int i = 0; i < 96; ++i)
            s = fmaf(v96[i], hw.f1w[i * 256 + tid], s);
        h1[tid] = fmaxf(s, 0.f);
    }
    __syncthreads();
    {
        float s = hw.f2b[tid];
        for (int i = 0; i < 256; ++i)
            s = fmaf(h1[i], hw.f2w[i * 256 + tid], s);
        h2[tid] = fmaxf(s, 0.f);
    }
    __syncthreads();
    if (tid < 128) {
        float s = hw.r1b[tid];
        for (int i = 0; i < 256; ++i)
            s = fmaf(h2[i], hw.r1w[i * 128 + tid], s);
        h3[tid] = fmaxf(s, 0.f);
    }
    __syncthreads();
    if (tid < 10) {
        float s = hw.r2b[tid];
        for (int i = 0; i < 128; ++i)
            s = fmaf(h3[i], hw.r2w[i * 10 + tid], s);
        out[b * 10 + tid] = s;
    }
}

// ---------------------------------------------------------------------------
extern "C" void kernel_launch(void* const* d_in, const int* in_sizes, int n_in,
                              void* d_out, int out_size, void* d_ws, size_t ws_size,
                              hipStream_t stream)
{
    const float* x  = (const float*)d_in[0];
    const float* pw = (const float*)d_in[1];
    const float* pb = (const float*)d_in[2];

    const float* c1w0 = (const float*)d_in[5];  const float* c1b0 = (const float*)d_in[6];
    const float* c2w0 = (const float*)d_in[7];  const float* c2b0 = (const float*)d_in[8];
    const float* dw0  = (const float*)d_in[9];  const float* db0  = (const float*)d_in[10];
    const float* c1w1 = (const float*)d_in[11]; const float* c1b1 = (const float*)d_in[12];
    const float* c2w1 = (const float*)d_in[13]; const float* c2b1 = (const float*)d_in[14];
    const float* dw1  = (const float*)d_in[15]; const float* db1  = (const float*)d_in[16];
    const float* c1w2 = (const float*)d_in[17]; const float* c1b2 = (const float*)d_in[18];
    const float* c2w2 = (const float*)d_in[19]; const float* c2b2 = (const float*)d_in[20];
    const float* dw2  = (const float*)d_in[21]; const float* db2  = (const float*)d_in[22];

    HeadW hw = { (const float*)d_in[3],  (const float*)d_in[4],
                 (const float*)d_in[23], (const float*)d_in[24],
                 (const float*)d_in[25], (const float*)d_in[26],
                 (const float*)d_in[27], (const float*)d_in[28],
                 (const float*)d_in[29], (const float*)d_in[30],
                 (const float*)d_in[31], (const float*)d_in[32] };

    float* W   = (float*)d_ws;
    float* h   = W + WS_H;
    float* sq  = W + WS_SQ;
    float* acc = W + WS_ACC;
    float* wT  = W + WS_WT;
    float* a0  = W + WS_A0;
    float* o0  = W + WS_O0;
    float* a1  = W + WS_A1;
    float* o1  = W + WS_O1;
    float* a2  = W + WS_A2;
    float* y   = W + WS_Y;

    WSegs S;
    const float* srcs[9] = {c1w0, c2w0, dw0, c1w1, c2w1, dw1, c1w2, c2w2, dw2};
    const int k3s[9]   = {24, 96, 8, 96, 192, 32, 192, 384, 64};
    const int col2[9]  = {5, 5, 5, 6, 6, 6, 7, 7, 7};
    const int offs[10] = {WT_C1_0, WT_C2_0, WT_DW0, WT_C1_1, WT_C2_1, WT_DW1,
                          WT_C1_2, WT_C2_2, WT_DW2, WT_TOTAL};
    for (int i = 0; i < 9; ++i) { S.src[i] = srcs[i]; S.k3[i] = k3s[i]; S.colog2[i] = col2[i]; }
    for (int i = 0; i < 10; ++i) S.off[i] = offs[i];

    k_project<<<(B_ * T_ * LH_) / 256, 256, 0, stream>>>(x, pw, pb, h, sq, acc);
    k_wT<<<(WT_TOTAL + 255) / 256, 256, 0, stream>>>(S, wT);

    k_conv<8, 32, 1, 27><<<dim3(4, B_), 256, 0, stream>>>(
        x, T_ * C_, 995, wT + WT_C1_0, c1b0, a0);
    k_convres<32, 32, 1, 25, 8><<<dim3(4, B_), 256, 0, stream>>>(
        a0, 27 * 32, wT + WT_C2_0, c2b0, x, T_ * C_, 999, wT + WT_DW0, db0, o0);
    k_conv<32, 64, 2, 21><<<dim3(6, B_), 256, 0, stream>>>(
        o0, 25 * 32, 0, wT + WT_C1_1, c1b1, a1);
    k_convres<64, 64, 2, 17, 32><<<dim3(5, B_), 256, 0, stream>>>(
        a1, 21 * 64, wT + WT_C2_1, c2b1, o0, 25 * 32, 8, wT + WT_DW1, db1, o1);
    k_conv<64, 128, 4, 9><<<dim3(5, B_), 256, 0, stream>>>(
        o1, 17 * 64, 0, wT + WT_C1_2, c1b2, a2);
    k_convres<128, 128, 4, 1, 64><<<dim3(1, B_), 256, 0, stream>>>(
        a2, 9 * 128, wT + WT_C2_2, c2b2, o1, 17 * 64, 16, wT + WT_DW2, db2, y);

    // preferred big-LDS laplace; deterministic host-side fallback if the
    // dynamic-LDS limit can't be raised on this runtime.
    const int dyn_lds = (1024 * SPAD + 16 * 32) * (int)sizeof(float);  // 149504
    hipError_t ae = hipFuncSetAttribute(
        reinterpret_cast<const void*>(k_laplace_big),
        hipFuncAttributeMaxDynamicSharedMemorySize, dyn_lds);
    if (ae == hipSuccess) {
        k_laplace_big<<<B_ * (T_ / 32), 1024, dyn_lds, stream>>>(h, sq, acc);
    } else {
        k_laplace_tiled<<<(B_ * T_) / 8, 256, 0, stream>>>(h, sq, acc);
    }

    k_head<<<B_, 256, 0, stream>>>(y, acc, hw, (float*)d_out);
}

// Round 7
// 288.617 us; speedup vs baseline: 4.3762x; 4.3762x over previous
//
#include <hip/hip_runtime.h>
#include <hip/hip_bf16.h>

#define B_  32
#define T_  1024
#define C_  8
#define K_  10
#define LH_ 32

// ---------------------------------------------------------------------------
// workspace layout (floats)
// ---------------------------------------------------------------------------
#define WS_H    0
#define WS_SQ   1048576            // B*T*32
#define WS_ACC  (WS_SQ + 32768)
#define WS_WT   (WS_ACC + 1024)   // transposed weights, 106496 floats
#define WS_A0   (WS_WT + 106496)  // [B][27][32]
#define WS_O0   (WS_A0 + 27648)   // [B][25][32]
#define WS_A1   (WS_O0 + 25600)   // [B][21][64]
#define WS_O1   (WS_A1 + 43008)   // [B][17][64]
#define WS_A2   (WS_O1 + 34816)   // [B][9][128]
#define WS_Y    (WS_A2 + 36864)   // [B][128]

#define WT_C1_0 0
#define WT_C2_0 768
#define WT_DW0  3840
#define WT_C1_1 4096
#define WT_C2_1 10240
#define WT_DW1  22528
#define WT_C1_2 24576
#define WT_C2_2 49152
#define WT_DW2  98304
#define WT_TOTAL 106496

// ---------------------------------------------------------------------------
// K1: h = x @ pw + pb (fp32), sq = ||h||^2, zero acc
// ---------------------------------------------------------------------------
__global__ __launch_bounds__(256) void k_project(
    const float* __restrict__ x,
    const float* __restrict__ pw,
    const float* __restrict__ pb,
    float* __restrict__ h, float* __restrict__ sq, float* __restrict__ acc)
{
    int gid = blockIdx.x * 256 + threadIdx.x;
    if (gid < B_ * LH_) acc[gid] = 0.f;
    int row = gid >> 5;
    int i   = gid & 31;
    const float* xr = x + (size_t)row * C_;
    float4 x0 = *(const float4*)xr;
    float4 x1 = *(const float4*)(xr + 4);
    float hv = pb[i];
    hv = fmaf(x0.x, pw[0 * LH_ + i], hv);
    hv = fmaf(x0.y, pw[1 * LH_ + i], hv);
    hv = fmaf(x0.z, pw[2 * LH_ + i], hv);
    hv = fmaf(x0.w, pw[3 * LH_ + i], hv);
    hv = fmaf(x1.x, pw[4 * LH_ + i], hv);
    hv = fmaf(x1.y, pw[5 * LH_ + i], hv);
    hv = fmaf(x1.z, pw[6 * LH_ + i], hv);
    hv = fmaf(x1.w, pw[7 * LH_ + i], hv);
    h[(size_t)row * LH_ + i] = hv;
    float e = hv * hv;
#pragma unroll
    for (int off = 1; off < 32; off <<= 1) e += __shfl_xor(e, off, 64);
    if (i == 0) sq[row] = e;
}

// ---------------------------------------------------------------------------
// DPP full-wave min (u32) — verified correct on HW in R6 run.
// row_shr 1/2/4/8 within 16-lane rows, row_bcast 15/31, result in lane 63.
// ---------------------------------------------------------------------------
__device__ __forceinline__ unsigned wave_min_u32(unsigned v)
{
#define DPP_MIN(ctrl) \
    v = min(v, (unsigned)__builtin_amdgcn_update_dpp((int)v, (int)v, ctrl, 0xF, 0xF, false))
    DPP_MIN(0x111);  // row_shr:1
    DPP_MIN(0x112);  // row_shr:2
    DPP_MIN(0x114);  // row_shr:4
    DPP_MIN(0x118);  // row_shr:8
    DPP_MIN(0x142);  // row_bcast:15
    DPP_MIN(0x143);  // row_bcast:31
#undef DPP_MIN
    return (unsigned)__builtin_amdgcn_readlane((int)v, 63);
}

// ---------------------------------------------------------------------------
// K2: R4 structure (proven 123us) + DPP selection + double-buffered tiles
// (1 barrier per tile instead of 2).
// ---------------------------------------------------------------------------
#define STILE 128
#define SPAD  36

__global__ __launch_bounds__(256, 2) void k_laplace(
    const float* __restrict__ h, const float* __restrict__ sq,
    float* __restrict__ acc)
{
    __shared__ float tile[2][STILE * SPAD];   // 36 KB double buffer
    __shared__ float wacc[4 * 32];
    __shared__ float qbuf[8 * 32];

    const int tid = threadIdx.x;
    const int wv  = tid >> 6;
    const int ln  = tid & 63;
    const int b   = blockIdx.x >> 7;
    const int t0  = (blockIdx.x & 127) * 8;
    const int tA  = t0 + wv * 2;
    const int tB  = tA + 1;

    const float* hb  = h  + (size_t)b * T_ * LH_;
    const float* sqb = sq + b * T_;

    if (ln < 32) {
        qbuf[(wv * 2 + 0) * 32 + ln] = hb[tA * LH_ + ln];
        qbuf[(wv * 2 + 1) * 32 + ln] = hb[tB * LH_ + ln];
    }
    float qA[32], qB[32];
#pragma unroll
    for (int i = 0; i < 32; ++i) { qA[i] = hb[tA * LH_ + i]; qB[i] = hb[tB * LH_ + i]; }
    const float sqA = sqb[tA], sqB = sqb[tB];

    // stage directly from the lane's own coalesced slice (r = tid>>3, c4 = tid&7)
    const int st_r  = tid >> 3, st_c4 = tid & 7;
    auto stage = [&](int buf, int s_base) {
#pragma unroll
        for (int u = 0; u < 4; ++u) {
            int r = st_r + u * 32;
            float4 val = *(const float4*)(hb + (size_t)(s_base + r) * LH_ + st_c4 * 4);
            *(float4*)&tile[buf][r * SPAD + st_c4 * 4] = val;
        }
    };

    unsigned kA[16], kB[16];

    stage(0, 0);
    __syncthreads();

    for (int tl = 0; tl < T_ / STILE; ++tl) {
        const int s_base = tl * STILE;
        const int cur = tl & 1;
        if (tl + 1 < T_ / STILE) stage(cur ^ 1, s_base + STILE);
#pragma unroll
        for (int sub = 0; sub < 2; ++sub) {
            const int sr = sub * 64 + ln;
            const int s  = s_base + sr;
            const float* hs = &tile[cur][sr * SPAD];
            float dA = 0.f, dB = 0.f;
#pragma unroll
            for (int q4 = 0; q4 < 8; ++q4) {
                float4 hv4 = *(const float4*)(hs + q4 * 4);
                dA = fmaf(hv4.x, qA[q4 * 4 + 0], dA); dB = fmaf(hv4.x, qB[q4 * 4 + 0], dB);
                dA = fmaf(hv4.y, qA[q4 * 4 + 1], dA); dB = fmaf(hv4.y, qB[q4 * 4 + 1], dB);
                dA = fmaf(hv4.z, qA[q4 * 4 + 2], dA); dB = fmaf(hv4.z, qB[q4 * 4 + 2], dB);
                dA = fmaf(hv4.w, qA[q4 * 4 + 3], dA); dB = fmaf(hv4.w, qB[q4 * 4 + 3], dB);
            }
            const float sqs = sqb[s];
            float d2A = fmaxf(sqA + sqs - 2.f * dA, 0.f);
            float d2B = fmaxf(sqB + sqs - 2.f * dB, 0.f);
            unsigned keyA = (__float_as_uint(d2A) & 0xFFFFFC00u) | (unsigned)s;
            unsigned keyB = (__float_as_uint(d2B) & 0xFFFFFC00u) | (unsigned)s;
            if (s == tA) keyA = 0xFFFFFC00u | (unsigned)s;
            if (s == tB) keyB = 0xFFFFFC00u | (unsigned)s;
            kA[tl * 2 + sub] = keyA;
            kB[tl * 2 + sub] = keyB;
        }
        __syncthreads();   // staging of nxt done; cur free for reuse next iter
    }

    float racc = 0.f;

    auto process = [&](unsigned (&ku)[16], int qslot) {
        int   sk[K_];
        float wk[K_];
        unsigned g2[4];
#pragma unroll
        for (int g = 0; g < 4; ++g)
            g2[g] = min(min(ku[4 * g], ku[4 * g + 1]), min(ku[4 * g + 2], ku[4 * g + 3]));
#pragma unroll
        for (int r = 0; r < K_; ++r) {
            unsigned m  = min(min(g2[0], g2[1]), min(g2[2], g2[3]));
            unsigned mu = wave_min_u32(m);            // wave-uniform, pure VALU
            int s_win = (int)(mu & 1023u);
            sk[r] = s_win;
            wk[r] = __expf(-0.5f * __uint_as_float(mu & 0xFFFFFC00u));
            const int  c = s_win >> 6;                // SGPR -> scalar branch
            const bool winlane = ((s_win & 63) == ln);
#pragma unroll
            for (int cc = 0; cc < 16; ++cc) if (cc == c) {
                ku[cc] = winlane ? 0xFFFFFFFFu : ku[cc];
                const int g = cc >> 2;
                g2[g] = min(min(ku[4 * g], ku[4 * g + 1]), min(ku[4 * g + 2], ku[4 * g + 3]));
            }
        }
        const int i = ln & 31;
        const float qi = qbuf[qslot * 32 + i];
        float W = 0.f, sm = 0.f;
#pragma unroll
        for (int k = 0; k < K_; ++k) {
            W += wk[k];
            sm = fmaf(wk[k], hb[(size_t)sk[k] * LH_ + i], sm);
        }
        sm *= __builtin_amdgcn_rcpf(W + 1e-8f);
        float z  = qi - sm;
        float ex = __expf(2.f * z);                   // tanh(z) = 1 - 2/(e^{2z}+1)
        racc += 1.f - 2.f * __builtin_amdgcn_rcpf(ex + 1.f);
    };

    process(kA, wv * 2 + 0);
    process(kB, wv * 2 + 1);

    if (ln < 32) wacc[wv * 32 + ln] = racc;
    __syncthreads();
    if (tid < 32) {
        float tot = wacc[tid] + wacc[32 + tid] + wacc[64 + tid] + wacc[96 + tid];
        atomicAdd(&acc[b * LH_ + tid], tot);
    }
}

// ---------------------------------------------------------------------------
// Weight transpose + TCN stages + head (unchanged, proven)
// ---------------------------------------------------------------------------
struct WSegs { const float* src[9]; int k3[9]; int colog2[9]; int off[10]; };

__global__ __launch_bounds__(256) void k_wT(WSegs S, float* __restrict__ wT)
{
    int gid = blockIdx.x * 256 + threadIdx.x;
    if (gid >= WT_TOTAL) return;
#pragma unroll
    for (int s = 0; s < 9; ++s) {
        if (gid >= S.off[s] && gid < S.off[s + 1]) {
            int local = gid - S.off[s];
            int k = local >> S.colog2[s];
            int o = local & ((1 << S.colog2[s]) - 1);
            wT[gid] = S.src[s][o * S.k3[s] + k];
        }
    }
}

template<int CI, int CO, int DIL, int ROWS>
__global__ __launch_bounds__(256) void k_conv(
    const float* __restrict__ in, int in_bs, int in_roff,
    const float* __restrict__ wT, const float* __restrict__ bias,
    float* __restrict__ out)
{
    const int e = blockIdx.x * 256 + threadIdx.x;
    const int b = blockIdx.y;
    if (e >= ROWS * CO) return;
    const int r = e / CO, o = e % CO;
    const float* inb = in + (size_t)b * in_bs + (size_t)in_roff * CI;
    float s = bias[o];
    for (int i = 0; i < CI; ++i)
#pragma unroll
        for (int j = 0; j < 3; ++j)
            s = fmaf(wT[(i * 3 + j) * CO + o], inb[(r + DIL * j) * CI + i], s);
    out[(size_t)b * (ROWS * CO) + e] = fmaxf(s, 0.f);
}

template<int CI, int CO, int DIL, int ROWS, int RCI>
__global__ __launch_bounds__(256) void k_convres(
    const float* __restrict__ in, int in_bs,
    const float* __restrict__ wT2, const float* __restrict__ b2,
    const float* __restrict__ res, int res_bs, int res_roff,
    const float* __restrict__ wTd, const float* __restrict__ db,
    float* __restrict__ out)
{
    const int e = blockIdx.x * 256 + threadIdx.x;
    const int b = blockIdx.y;
    if (e >= ROWS * CO) return;
    const int r = e / CO, o = e % CO;
    const float* inb = in + (size_t)b * in_bs;
    float s = b2[o];
    for (int i = 0; i < CI; ++i)
#pragma unroll
        for (int j = 0; j < 3; ++j)
            s = fmaf(wT2[(i * 3 + j) * CO + o], inb[(r + DIL * j) * CI + i], s);
    s = fmaxf(s, 0.f);
    const float* rb = res + (size_t)b * res_bs + (size_t)(res_roff + r) * RCI;
    float rs = db[o];
    for (int i = 0; i < RCI; ++i)
        rs = fmaf(wTd[i * CO + o], rb[i], rs);
    out[(size_t)b * (ROWS * CO) + e] = fmaxf(s + rs, 0.f);
}

struct HeadW {
    const float *ow, *ob, *head_w, *head_b;
    const float *f1w, *f1b, *f2w, *f2b, *r1w, *r1b, *r2w, *r2b;
};

__global__ __launch_bounds__(256) void k_head(
    const float* __restrict__ y, const float* __restrict__ acc,
    HeadW hw, float* __restrict__ out)
{
    const int b = blockIdx.x, tid = threadIdx.x;
    __shared__ float yv[128], v96[96], h1[256], h2[256], h3[128];

    if (tid < 128) yv[tid] = y[b * 128 + tid];
    else if (tid < 160) {
        int j = tid - 128;
        float s = hw.ob[j];
        for (int i = 0; i < 32; ++i)
            s = fmaf(acc[b * 32 + i] * (1.f / 1024.f), hw.ow[i * 32 + j], s);
        v96[j] = s;
    }
    __syncthreads();
    if (tid < 64) {
        float s = hw.head_b[tid];
        for (int i = 0; i < 128; ++i)
            s = fmaf(yv[i], hw.head_w[i * 64 + tid], s);
        v96[32 + tid] = s;
    }
    __syncthreads();
    {
        float s = hw.f1b[tid];
        for (int i = 0; i < 96; ++i)
            s = fmaf(v96[i], hw.f1w[i * 256 + tid], s);
        h1[tid] = fmaxf(s, 0.f);
    }
    __syncthreads();
    {
        float s = hw.f2b[tid];
        for (int i = 0; i < 256; ++i)
            s = fmaf(h1[i], hw.f2w[i * 256 + tid], s);
        h2[tid] = fmaxf(s, 0.f);
    }
    __syncthreads();
    if (tid < 128) {
        float s = hw.r1b[tid];
        for (int i = 0; i < 256; ++i)
            s = fmaf(h2[i], hw.r1w[i * 128 + tid], s);
        h3[tid] = fmaxf(s, 0.f);
    }
    __syncthreads();
    if (tid < 10) {
        float s = hw.r2b[tid];
        for (int i = 0; i < 128; ++i)
            s = fmaf(h3[i], hw.r2w[i * 10 + tid], s);
        out[b * 10 + tid] = s;
    }
}

// ---------------------------------------------------------------------------
extern "C" void kernel_launch(void* const* d_in, const int* in_sizes, int n_in,
                              void* d_out, int out_size, void* d_ws, size_t ws_size,
                              hipStream_t stream)
{
    const float* x  = (const float*)d_in[0];
    const float* pw = (const float*)d_in[1];
    const float* pb = (const float*)d_in[2];

    const float* c1w0 = (const float*)d_in[5];  const float* c1b0 = (const float*)d_in[6];
    const float* c2w0 = (const float*)d_in[7];  const float* c2b0 = (const float*)d_in[8];
    const float* dw0  = (const float*)d_in[9];  const float* db0  = (const float*)d_in[10];
    const float* c1w1 = (const float*)d_in[11]; const float* c1b1 = (const float*)d_in[12];
    const float* c2w1 = (const float*)d_in[13]; const float* c2b1 = (const float*)d_in[14];
    const float* dw1  = (const float*)d_in[15]; const float* db1  = (const float*)d_in[16];
    const float* c1w2 = (const float*)d_in[17]; const float* c1b2 = (const float*)d_in[18];
    const float* c2w2 = (const float*)d_in[19]; const float* c2b2 = (const float*)d_in[20];
    const float* dw2  = (const float*)d_in[21]; const float* db2  = (const float*)d_in[22];

    HeadW hw = { (const float*)d_in[3],  (const float*)d_in[4],
                 (const float*)d_in[23], (const float*)d_in[24],
                 (const float*)d_in[25], (const float*)d_in[26],
                 (const float*)d_in[27], (const float*)d_in[28],
                 (const float*)d_in[29], (const float*)d_in[30],
                 (const float*)d_in[31], (const float*)d_in[32] };

    float* W   = (float*)d_ws;
    float* h   = W + WS_H;
    float* sq  = W + WS_SQ;
    float* acc = W + WS_ACC;
    float* wT  = W + WS_WT;
    float* a0  = W + WS_A0;
    float* o0  = W + WS_O0;
    float* a1  = W + WS_A1;
    float* o1  = W + WS_O1;
    float* a2  = W + WS_A2;
    float* y   = W + WS_Y;

    WSegs S;
    const float* srcs[9] = {c1w0, c2w0, dw0, c1w1, c2w1, dw1, c1w2, c2w2, dw2};
    const int k3s[9]   = {24, 96, 8, 96, 192, 32, 192, 384, 64};
    const int col2[9]  = {5, 5, 5, 6, 6, 6, 7, 7, 7};
    const int offs[10] = {WT_C1_0, WT_C2_0, WT_DW0, WT_C1_1, WT_C2_1, WT_DW1,
                          WT_C1_2, WT_C2_2, WT_DW2, WT_TOTAL};
    for (int i = 0; i < 9; ++i) { S.src[i] = srcs[i]; S.k3[i] = k3s[i]; S.colog2[i] = col2[i]; }
    for (int i = 0; i < 10; ++i) S.off[i] = offs[i];

    k_project<<<(B_ * T_ * LH_) / 256, 256, 0, stream>>>(x, pw, pb, h, sq, acc);
    k_wT<<<(WT_TOTAL + 255) / 256, 256, 0, stream>>>(S, wT);

    k_conv<8, 32, 1, 27><<<dim3(4, B_), 256, 0, stream>>>(
        x, T_ * C_, 995, wT + WT_C1_0, c1b0, a0);
    k_convres<32, 32, 1, 25, 8><<<dim3(4, B_), 256, 0, stream>>>(
        a0, 27 * 32, wT + WT_C2_0, c2b0, x, T_ * C_, 999, wT + WT_DW0, db0, o0);
    k_conv<32, 64, 2, 21><<<dim3(6, B_), 256, 0, stream>>>(
        o0, 25 * 32, 0, wT + WT_C1_1, c1b1, a1);
    k_convres<64, 64, 2, 17, 32><<<dim3(5, B_), 256, 0, stream>>>(
        a1, 21 * 64, wT + WT_C2_1, c2b1, o0, 25 * 32, 8, wT + WT_DW1, db1, o1);
    k_conv<64, 128, 4, 9><<<dim3(5, B_), 256, 0, stream>>>(
        o1, 17 * 64, 0, wT + WT_C1_2, c1b2, a2);
    k_convres<128, 128, 4, 1, 64><<<dim3(1, B_), 256, 0, stream>>>(
        a2, 9 * 128, wT + WT_C2_2, c2b2, o1, 17 * 64, 16, wT + WT_DW2, db2, y);

    k_laplace<<<(B_ * T_) / 8, 256, 0, stream>>>(h, sq, acc);
    k_head<<<B_, 256, 0, stream>>>(y, acc, hw, (float*)d_out);
}